// Round 12
// baseline (382.928 us; speedup 1.0000x reference)
//
#include <hip/hip_runtime.h>
#include <hip/hip_bf16.h>

typedef _Float16 half8 __attribute__((ext_vector_type(8)));
typedef float f32x4 __attribute__((ext_vector_type(4)));

#define B_SZ 64
#define T_SZ 512
#define E_SZ 768
#define H_SZ 256
#define V_SZ 3072

// workspace layout (bytes)
#define WS_P     0u          // _Float16 P[3072][256] = emb @ Wxh   1,572,864 B
#define WS_WF    1572864u    // _Float16 Wf[65536] Whh MFMA-B         131,072 B

// fast tanh: 1 - 2/(1+exp(2x)); exact at +/-inf, ~1e-6 rel err
static __device__ __forceinline__ float fast_tanh(float x) {
  float e = __builtin_amdgcn_exp2f(x * 2.8853900817779268f); // exp(2x)
  return 1.0f - 2.0f * __builtin_amdgcn_rcpf(1.0f + e);
}

// ---------------- k01: Wf conversion (blocks 48-111) + P projection (0-47) ----
// Launch-count reduction: R8->R9 accounting puts each launch at ~20-30 us of
// gap+ramp. k0 is deleted by (a) staging k1's B panels DIRECTLY from Wxh
// (same values the Wtf path produced -- 8 strided f32 gathers per fragment
// slot; at 48 blocks the extra loads cost ~3-5 us) and (b) folding the Wf
// conversion into spare blocks of the same kernel (no intra-kernel
// producer-consumer; k2 consumes Wf/P via stream order).
__global__ __launch_bounds__(256) void k01(
    const float* __restrict__ emb,
    const float* __restrict__ Wxh,
    const float* __restrict__ Whh,
    _Float16* __restrict__ P,
    _Float16* __restrict__ Wf)
{
  const int tid = threadIdx.x;
  if (blockIdx.x >= 48) {
    // Wf: src (row,col) -> kt=row>>5, quad=(row>>3)&3, j=row&7, nt=col>>4,
    //     lane=(quad<<4)|(col&15), flat = ((nt*8+kt)*64+lane)*8 + j
    const int base = (blockIdx.x - 48) * 1024;
#pragma unroll
    for (int k = 0; k < 4; ++k) {
      const int g0 = base + k * 256 + tid;        // covers [0, 65536) exactly
      const int row = g0 >> 8, col = g0 & 255;
      const float v = Whh[g0];
      const int kt = row >> 5, quad = (row >> 3) & 3, j = row & 7;
      const int nt = col >> 4;
      const int lane = (quad << 4) | (col & 15);
      Wf[(((size_t)(nt * 8 + kt) * 64 + lane) * 8) + j] = (_Float16)v;
    }
    return;
  }
  // ---- projection: P[r,:] = emb[r,:] @ Wxh, r = blk*64 .. +63 (R8 k1 core)
  const int w    = tid >> 6;
  const int lane = tid & 63;
  const int m16  = lane & 15;
  const int quad = lane >> 4;
  const int r = blockIdx.x * 64 + w * 16 + m16;     // vocab row, 0..3071
  const float* Arow = emb + (size_t)r * E_SZ + quad * 8;   // A[m][k=quad*8+j]

  __shared__ __align__(16) _Float16 bp[2][16 * 64 * 8]; // 2 x 16KB fragment panels

  int n_[4], kb_[4];
#pragma unroll
  for (int pp = 0; pp < 4; ++pp) {
    int f = tid + 256 * pp;
    n_[pp]  = ((f >> 6) << 4) | (f & 15);
    kb_[pp] = (f >> 4) & 3;
  }

  // B-fragment gather from Wxh: slot (f, j) = Wxh[ki*32 + kb*8 + j][n_]
  f32x4 s0[4], s1[4];          // s0[pp]=j 0..3, s1[pp]=j 4..7 (f32, cvt at write)
#define LOADPAN(KI) { \
  _Pragma("unroll") \
  for (int pp = 0; pp < 4; ++pp) { \
    const float* src = Wxh + (size_t)((KI) * 32 + kb_[pp] * 8) * H_SZ + n_[pp]; \
    s0[pp][0] = src[0 * H_SZ]; s0[pp][1] = src[1 * H_SZ]; \
    s0[pp][2] = src[2 * H_SZ]; s0[pp][3] = src[3 * H_SZ]; \
    s1[pp][0] = src[4 * H_SZ]; s1[pp][1] = src[5 * H_SZ]; \
    s1[pp][2] = src[6 * H_SZ]; s1[pp][3] = src[7 * H_SZ]; \
  } }
#define WRITEPAN(BUF) { \
  _Pragma("unroll") \
  for (int pp = 0; pp < 4; ++pp) { \
    half8 hh; \
    _Pragma("unroll") \
    for (int j = 0; j < 4; ++j) { hh[j] = (_Float16)s0[pp][j]; hh[4 + j] = (_Float16)s1[pp][j]; } \
    *(half8*)(bp[BUF] + (size_t)(tid + 256 * pp) * 8) = hh; \
  } }

  LOADPAN(0)
  f32x4 af0 = *(const f32x4*)(Arow);
  f32x4 af1 = *(const f32x4*)(Arow + 4);

  f32x4 acc[16];
#pragma unroll
  for (int n = 0; n < 16; ++n) { f32x4 z = {0.f, 0.f, 0.f, 0.f}; acc[n] = z; }

  WRITEPAN(0)
  __syncthreads();

#pragma unroll 1
  for (int ki = 0; ki < 24; ++ki) {
    const _Float16* cur = bp[ki & 1];
    f32x4 af0n = af0, af1n = af1;
    if (ki < 23) {                            // prefetch next panel + next A
      LOADPAN(ki + 1)
      af0n = *(const f32x4*)(Arow + (ki + 1) * 32);
      af1n = *(const f32x4*)(Arow + (ki + 1) * 32 + 4);
    }
    half8 a;
#pragma unroll
    for (int e = 0; e < 4; ++e) { a[e] = (_Float16)af0[e]; a[4 + e] = (_Float16)af1[e]; }
#pragma unroll
    for (int nt = 0; nt < 16; ++nt) {
      half8 bb = *(const half8*)(cur + (size_t)(nt * 64 + lane) * 8);
      acc[nt] = __builtin_amdgcn_mfma_f32_16x16x32_f16(a, bb, acc[nt], 0, 0, 0);
    }
    if (ki < 23) {                            // write next buffer, one barrier
      WRITEPAN((ki + 1) & 1)
      __syncthreads();
    }
    af0 = af0n; af1 = af1n;
  }
  const int rbase = blockIdx.x * 64 + w * 16 + quad * 4;  // C/D: col=lane&15, row=quad*4+reg
#pragma unroll
  for (int nt = 0; nt < 16; ++nt) {
    const int col = nt * 16 + m16;
#pragma unroll
    for (int rg = 0; rg < 4; ++rg) {
      P[(size_t)(rbase + rg) * H_SZ + col] = (_Float16)acc[nt][rg];
    }
  }
#undef LOADPAN
#undef WRITEPAN
}

// ---------------- k2: R8 MFMA recurrence + WIDE fused output projection ------
// Recurrence loop verbatim from the proven 244.6-us R8 kernel. Fused tail
// fixes R9's mistake: all 12 v-chunks live per thread -> 24 independent Wy
// loads in flight per jj-pair (R9 had 4 -> latency-serialized, +75 us).
// Est. tail ~8 us; deletes the k3 launch (~25-30 us) and hbuf.
#define LDFRAG(C, KT, R0, R1, R2, R3) { \
  uint4 q = Wf4[(((size_t)(w * 4 + C) * 8 + KT) * 64) + lane]; \
  asm volatile("v_accvgpr_write_b32 a" #R0 ", %0" :: "v"(q.x) : "a" #R0); \
  asm volatile("v_accvgpr_write_b32 a" #R1 ", %0" :: "v"(q.y) : "a" #R1); \
  asm volatile("v_accvgpr_write_b32 a" #R2 ", %0" :: "v"(q.z) : "a" #R2); \
  asm volatile("v_accvgpr_write_b32 a" #R3 ", %0" :: "v"(q.w) : "a" #R3); }

#define MFMA_K0(A0, Z) \
  asm volatile( \
    "v_mfma_f32_16x16x32_f16 %[t0], %[a], a[0:3],   %[z]\n\t" \
    "v_mfma_f32_16x16x32_f16 %[t1], %[a], a[32:35], %[z]\n\t" \
    "v_mfma_f32_16x16x32_f16 %[t2], %[a], a[64:67], %[z]\n\t" \
    "v_mfma_f32_16x16x32_f16 %[t3], %[a], a[96:99], %[z]" \
    : [t0] "=&v"(acc0), [t1] "=&v"(acc1), [t2] "=&v"(acc2), [t3] "=&v"(acc3) \
    : [a] "v"(A0), [z] "v"(Z));

#define MFMA_KT(A0, B0, B1, B2, B3) \
  asm volatile( \
    "v_mfma_f32_16x16x32_f16 %[t0], %[a], a[" #B0 "], %[t0]\n\t" \
    "v_mfma_f32_16x16x32_f16 %[t1], %[a], a[" #B1 "], %[t1]\n\t" \
    "v_mfma_f32_16x16x32_f16 %[t2], %[a], a[" #B2 "], %[t2]\n\t" \
    "v_mfma_f32_16x16x32_f16 %[t3], %[a], a[" #B3 "], %[t3]" \
    : [t0] "+v"(acc0), [t1] "+v"(acc1), [t2] "+v"(acc2), [t3] "+v"(acc3) \
    : [a] "v"(A0));

#define MFMA_K7(A0, B0, B1, B2, B3) \
  asm volatile( \
    "v_mfma_f32_16x16x32_f16 %[t0], %[a], a[" #B0 "], %[t0]\n\t" \
    "v_mfma_f32_16x16x32_f16 %[t1], %[a], a[" #B1 "], %[t1]\n\t" \
    "v_mfma_f32_16x16x32_f16 %[t2], %[a], a[" #B2 "], %[t2]\n\t" \
    "v_mfma_f32_16x16x32_f16 %[t3], %[a], a[" #B3 "], %[t3]\n\t" \
    "s_nop 7\n\t" \
    "s_nop 7" \
    : [t0] "+v"(acc0), [t1] "+v"(acc1), [t2] "+v"(acc2), [t3] "+v"(acc3) \
    : [a] "v"(A0));

__global__ __launch_bounds__(256) void k2_rnn(
    const _Float16* __restrict__ Wf,
    const _Float16* __restrict__ P,
    const int* __restrict__ idx,
    const float* __restrict__ Bh,
    const float* __restrict__ Wy,
    const float* __restrict__ By,
    float* __restrict__ out,
    float* __restrict__ hidout)
{
  const int b    = blockIdx.x;
  const int tid  = threadIdx.x;
  const int w    = tid >> 6;
  const int lane = tid & 63;
  const int quad = lane >> 4;
  __shared__ __align__(16) _Float16 hb[2][H_SZ];   // h as f16, double-buffered
  __shared__ float hf[H_SZ];                       // f32 h for fused logits
  const uint4* Wf4 = (const uint4*)Wf;

  LDFRAG(0,0,  0,  1,  2,  3)  LDFRAG(0,1,  4,  5,  6,  7)
  LDFRAG(0,2,  8,  9, 10, 11)  LDFRAG(0,3, 12, 13, 14, 15)
  LDFRAG(0,4, 16, 17, 18, 19)  LDFRAG(0,5, 20, 21, 22, 23)
  LDFRAG(0,6, 24, 25, 26, 27)  LDFRAG(0,7, 28, 29, 30, 31)
  LDFRAG(1,0, 32, 33, 34, 35)  LDFRAG(1,1, 36, 37, 38, 39)
  LDFRAG(1,2, 40, 41, 42, 43)  LDFRAG(1,3, 44, 45, 46, 47)
  LDFRAG(1,4, 48, 49, 50, 51)  LDFRAG(1,5, 52, 53, 54, 55)
  LDFRAG(1,6, 56, 57, 58, 59)  LDFRAG(1,7, 60, 61, 62, 63)
  LDFRAG(2,0, 64, 65, 66, 67)  LDFRAG(2,1, 68, 69, 70, 71)
  LDFRAG(2,2, 72, 73, 74, 75)  LDFRAG(2,3, 76, 77, 78, 79)
  LDFRAG(2,4, 80, 81, 82, 83)  LDFRAG(2,5, 84, 85, 86, 87)
  LDFRAG(2,6, 88, 89, 90, 91)  LDFRAG(2,7, 92, 93, 94, 95)
  LDFRAG(3,0, 96, 97, 98, 99)  LDFRAG(3,1,100,101,102,103)
  LDFRAG(3,2,104,105,106,107)  LDFRAG(3,3,108,109,110,111)
  LDFRAG(3,4,112,113,114,115)  LDFRAG(3,5,116,117,118,119)
  LDFRAG(3,6,120,121,122,123)  LDFRAG(3,7,124,125,126,127)

  const float bhj = Bh[tid];
  const int* idxb = idx + b * T_SZ;
  int rowA = idxb[2];                               // row for t=2 (next xA refill)
  int rowB = idxb[3];                               // row for t=3 (next xB refill)
  _Float16 xA = P[(size_t)idxb[0] * H_SZ + tid];    // x for t=0
  _Float16 xB = P[(size_t)idxb[1] * H_SZ + tid];    // x for t=1
  f32x4 zero4 = {0.f, 0.f, 0.f, 0.f};
  asm volatile("" : "+v"(zero4));        // pin: no remat-mov adjacent to MFMA srcC
  hb[1][tid] = (_Float16)0.f;            // t=0 reads buffer 1 = zeros
  float hval = 0.f;
  __syncthreads();

#define K2_STEP(HR, HW, XV)                                              \
  {                                                                      \
    const _Float16* hr = (HR);                                           \
    half8 va0 = *(const half8*)(hr +   0 + quad * 8);                    \
    half8 va1 = *(const half8*)(hr +  32 + quad * 8);                    \
    half8 va2 = *(const half8*)(hr +  64 + quad * 8);                    \
    half8 va3 = *(const half8*)(hr +  96 + quad * 8);                    \
    half8 va4 = *(const half8*)(hr + 128 + quad * 8);                    \
    half8 va5 = *(const half8*)(hr + 160 + quad * 8);                    \
    half8 va6 = *(const half8*)(hr + 192 + quad * 8);                    \
    half8 va7 = *(const half8*)(hr + 224 + quad * 8);                    \
    f32x4 acc0, acc1, acc2, acc3;                                        \
    MFMA_K0(va0, zero4)                                                  \
    MFMA_KT(va1,   4:7,  36:39,  68:71, 100:103)                         \
    MFMA_KT(va2,  8:11,  40:43,  72:75, 104:107)                         \
    MFMA_KT(va3, 12:15,  44:47,  76:79, 108:111)                         \
    MFMA_KT(va4, 16:19,  48:51,  80:83, 112:115)                         \
    MFMA_KT(va5, 20:23,  52:55,  84:87, 116:119)                         \
    MFMA_KT(va6, 24:27,  56:59,  88:91, 120:123)                         \
    MFMA_K7(va7, 28:31,  60:63,  92:95, 124:127)                         \
    float v0 = acc0[0], v1 = acc1[0], v2 = acc2[0], v3 = acc3[0];        \
    float ylo = (quad & 1) ? v1 : v0;                                    \
    float yhi = (quad & 1) ? v3 : v2;                                    \
    float y   = (quad & 2) ? yhi : ylo;     /* y = (h @ Whh)[tid] */     \
    hval = fast_tanh(y + (XV) + bhj);                                    \
    (HW)[tid] = (_Float16)hval;                                          \
    __syncthreads();                                                     \
  }

#pragma unroll 1
  for (int tt = 0; tt < 256; ++tt) {
    // ---- step A: t = 2tt, read hb[1], write hb[0]
    float xvA = (float)xA;                 // wait: xA load issued 1 iter (~2 steps) ago
    xA = P[(size_t)rowA * H_SZ + tid];     // refill for t = 2tt+2 (same register)
    int t4 = 2 * tt + 4; t4 = t4 > 511 ? 511 : t4;
    rowA = idxb[t4];                       // s_load, consumed next iteration
    K2_STEP(hb[1], hb[0], xvA)
    // ---- step B: t = 2tt+1, read hb[0], write hb[1]
    float xvB = (float)xB;
    xB = P[(size_t)rowB * H_SZ + tid];     // refill for t = 2tt+3
    int t5 = 2 * tt + 5; t5 = t5 > 511 ? 511 : t5;
    rowB = idxb[t5];
    K2_STEP(hb[0], hb[1], xvB)
  }
#undef K2_STEP
  hidout[b * H_SZ + tid] = hval;

  // ---- fused out-proj: out[b][:] = h @ Wy + By, 12 chunks wide per thread
  hf[tid] = hval;
  __syncthreads();
  float oacc[12];
#pragma unroll
  for (int c = 0; c < 12; ++c) oacc[c] = By[c * 256 + tid];
#pragma unroll 1
  for (int jj = 0; jj < H_SZ; jj += 2) {
    float h0 = hf[jj], h1 = hf[jj + 1];
    const float* r0 = Wy + (size_t)jj * V_SZ + tid;
    const float* r1 = r0 + V_SZ;
#pragma unroll
    for (int c = 0; c < 12; ++c) {
      oacc[c] += h0 * r0[c * 256];
      oacc[c] += h1 * r1[c * 256];
    }
  }
#pragma unroll
  for (int c = 0; c < 12; ++c)
    out[(size_t)b * V_SZ + c * 256 + tid] = oacc[c];
}

extern "C" void kernel_launch(void* const* d_in, const int* in_sizes, int n_in,
                              void* d_out, int out_size, void* d_ws, size_t ws_size,
                              hipStream_t stream)
{
  const int*   idx = (const int*)d_in[0];
  const float* emb = (const float*)d_in[1];
  const float* Wxh = (const float*)d_in[2];
  const float* Whh = (const float*)d_in[3];
  const float* Wy  = (const float*)d_in[4];
  const float* By  = (const float*)d_in[5];
  const float* Bh  = (const float*)d_in[6];

  char* ws = (char*)d_ws;
  _Float16* P  = (_Float16*)(ws + WS_P);
  _Float16* Wf = (_Float16*)(ws + WS_WF);

  float* out    = (float*)d_out;
  float* hidout = out + (size_t)B_SZ * V_SZ;

  k01   <<<112, 256, 0, stream>>>(emb, Wxh, Whh, P, Wf);
  k2_rnn<<<64, 256, 0, stream>>>(Wf, P, idx, Bh, Wy, By, out, hidout);
}

// Round 13
// 354.611 us; speedup vs baseline: 1.0799x; 1.0799x over previous
//
#include <hip/hip_runtime.h>
#include <hip/hip_bf16.h>

typedef _Float16 half8 __attribute__((ext_vector_type(8)));
typedef float f32x4 __attribute__((ext_vector_type(4)));

#define B_SZ 64
#define T_SZ 512
#define E_SZ 768
#define H_SZ 256
#define V_SZ 3072

// workspace layout (bytes)
#define WS_P     0u          // _Float16 P[3072][256] = emb @ Wxh   1,572,864 B
#define WS_WT    16777216u   // _Float16 Wtf[24][1024][8] (Wxh panels, frag order) 393,216 B
#define WS_WF    17170432u   // _Float16 Wf[65536] Whh MFMA-B    131,072 B
#define WS_H     17301504u   // float    h[64][256]               65,536 B

// fast tanh: 1 - 2/(1+exp(2x)); exact at +/-inf, ~1e-6 rel err
static __device__ __forceinline__ float fast_tanh(float x) {
  float e = __builtin_amdgcn_exp2f(x * 2.8853900817779268f); // exp(2x)
  return 1.0f - 2.0f * __builtin_amdgcn_rcpf(1.0f + e);
}

// ---------------- k0: prep f16 weight layouts (small) ----------------
// Coalesced reads + scattered 2B writes. Bijections (verified both ways):
// Wtf: src (e,n) -> ki=e>>5, kb=(e>>3)&3, j=e&7, f=((n>>4)<<6)|(kb<<4)|(n&15),
//      flat = ki*8192 + f*8 + j
// Wf:  src (row,col) -> kt=row>>5, quad=(row>>3)&3, j=row&7, nt=col>>4,
//      lane=(quad<<4)|(col&15), flat = ((nt*8+kt)*64+lane)*8 + j
__global__ __launch_bounds__(256) void k0_convert(
    const float* __restrict__ Wxh,
    const float* __restrict__ Whh,
    _Float16* __restrict__ Wtf,
    _Float16* __restrict__ Wf)
{
  int gid = blockIdx.x * 256 + threadIdx.x;           // 768 WGs = 196608
  if (gid < E_SZ * H_SZ) {                            // gid = e*256 + n (coalesced)
    int e = gid >> 8, n = gid & 255;
    float v = Wxh[gid];
    int ki = e >> 5, kb = (e >> 3) & 3, j = e & 7;
    int f  = ((n >> 4) << 6) | (kb << 4) | (n & 15);
    Wtf[(size_t)ki * 8192 + (size_t)f * 8 + j] = (_Float16)v;
  }
  if (gid < 65536) {                                  // gid = row*256 + col (coalesced)
    int row = gid >> 8, col = gid & 255;
    float v = Whh[gid];
    int kt = row >> 5, quad = (row >> 3) & 3, j = row & 7;
    int nt = col >> 4;
    int lane = (quad << 4) | (col & 15);
    Wf[(((size_t)(nt * 8 + kt) * 64 + lane) * 8) + j] = (_Float16)v;
  }
}

// ---------------- k1: P[v,:] = emb[v,:] @ Wxh  (MFMA f16, vocab table) ---------
// Projects the 3072-row table once (10.7x less work than per-(t,b)); k2
// gathers from P. Inner loop = proven R6 k1. Grid: 48 blocks x 64 rows.
__global__ __launch_bounds__(256) void k1_xproj(
    const float* __restrict__ emb,
    const _Float16* __restrict__ Wtf,
    _Float16* __restrict__ P)
{
  const int tid  = threadIdx.x;
  const int w    = tid >> 6;
  const int lane = tid & 63;
  const int m16  = lane & 15;
  const int quad = lane >> 4;
  const int r = blockIdx.x * 64 + w * 16 + m16;     // vocab row, 0..3071
  const float* Arow = emb + (size_t)r * E_SZ + quad * 8;   // A[m][k=quad*8+j]

  __shared__ __align__(16) _Float16 bp[2][16 * 64 * 8]; // 2 x 16KB fragment panels
  uint4 stg[4];
#pragma unroll
  for (int pp = 0; pp < 4; ++pp)
    stg[pp] = *(const uint4*)(Wtf + (size_t)(tid + 256 * pp) * 8);  // ki = 0
  f32x4 af0 = *(const f32x4*)(Arow);
  f32x4 af1 = *(const f32x4*)(Arow + 4);

  f32x4 acc[16];
#pragma unroll
  for (int n = 0; n < 16; ++n) { f32x4 z = {0.f, 0.f, 0.f, 0.f}; acc[n] = z; }

  // stage panel 0
#pragma unroll
  for (int pp = 0; pp < 4; ++pp)
    *(uint4*)(bp[0] + (size_t)(tid + 256 * pp) * 8) = stg[pp];
  __syncthreads();

#pragma unroll 1
  for (int ki = 0; ki < 24; ++ki) {
    const _Float16* cur = bp[ki & 1];
    f32x4 af0n = af0, af1n = af1;
    if (ki < 23) {                            // prefetch next panel + next A
#pragma unroll
      for (int pp = 0; pp < 4; ++pp)
        stg[pp] = *(const uint4*)(Wtf + (size_t)(ki + 1) * 8192
                                      + (size_t)(tid + 256 * pp) * 8);
      af0n = *(const f32x4*)(Arow + (ki + 1) * 32);
      af1n = *(const f32x4*)(Arow + (ki + 1) * 32 + 4);
    }
    half8 a;
#pragma unroll
    for (int e = 0; e < 4; ++e) { a[e] = (_Float16)af0[e]; a[4 + e] = (_Float16)af1[e]; }
#pragma unroll
    for (int nt = 0; nt < 16; ++nt) {
      half8 bb = *(const half8*)(cur + (size_t)(nt * 64 + lane) * 8);
      acc[nt] = __builtin_amdgcn_mfma_f32_16x16x32_f16(a, bb, acc[nt], 0, 0, 0);
    }
    if (ki < 23) {                            // write next buffer, one barrier
#pragma unroll
      for (int pp = 0; pp < 4; ++pp)
        *(uint4*)(bp[(ki + 1) & 1] + (size_t)(tid + 256 * pp) * 8) = stg[pp];
      __syncthreads();
    }
    af0 = af0n; af1 = af1n;
  }
  const int rbase = blockIdx.x * 64 + w * 16 + quad * 4;  // C/D: col=lane&15, row=quad*4+reg
#pragma unroll
  for (int nt = 0; nt < 16; ++nt) {
    const int col = nt * 16 + m16;
#pragma unroll
    for (int rg = 0; rg < 4; ++rg) {
      P[(size_t)(rbase + rg) * H_SZ + col] = (_Float16)acc[nt][rg];
    }
  }
}

// ---------------- k2: proven MFMA recurrence, per-K-tile asm split -----------
// Session-final form (244.6 us measured, R8). The per-CU step cost is a
// conservation law: 128 MFMA-equivalents/batch-step on 4 SIMDs (~620 cyc)
// regardless of wave/N split; 64 blocks forced by the per-step h-broadcast.
// Six structural alternatives measured worse. x gathered from P with the
// reload-in-place x2-unroll (full-iteration load cover); row ids s_loaded
// 2 steps ahead.
#define LDFRAG(C, KT, R0, R1, R2, R3) { \
  uint4 q = Wf4[(((size_t)(w * 4 + C) * 8 + KT) * 64) + lane]; \
  asm volatile("v_accvgpr_write_b32 a" #R0 ", %0" :: "v"(q.x) : "a" #R0); \
  asm volatile("v_accvgpr_write_b32 a" #R1 ", %0" :: "v"(q.y) : "a" #R1); \
  asm volatile("v_accvgpr_write_b32 a" #R2 ", %0" :: "v"(q.z) : "a" #R2); \
  asm volatile("v_accvgpr_write_b32 a" #R3 ", %0" :: "v"(q.w) : "a" #R3); }

// kt=0: fresh accumulators from pinned zero
#define MFMA_K0(A0, Z) \
  asm volatile( \
    "v_mfma_f32_16x16x32_f16 %[t0], %[a], a[0:3],   %[z]\n\t" \
    "v_mfma_f32_16x16x32_f16 %[t1], %[a], a[32:35], %[z]\n\t" \
    "v_mfma_f32_16x16x32_f16 %[t2], %[a], a[64:67], %[z]\n\t" \
    "v_mfma_f32_16x16x32_f16 %[t3], %[a], a[96:99], %[z]" \
    : [t0] "=&v"(acc0), [t1] "=&v"(acc1), [t2] "=&v"(acc2), [t3] "=&v"(acc3) \
    : [a] "v"(A0), [z] "v"(Z));

#define MFMA_KT(A0, B0, B1, B2, B3) \
  asm volatile( \
    "v_mfma_f32_16x16x32_f16 %[t0], %[a], a[" #B0 "], %[t0]\n\t" \
    "v_mfma_f32_16x16x32_f16 %[t1], %[a], a[" #B1 "], %[t1]\n\t" \
    "v_mfma_f32_16x16x32_f16 %[t2], %[a], a[" #B2 "], %[t2]\n\t" \
    "v_mfma_f32_16x16x32_f16 %[t3], %[a], a[" #B3 "], %[t3]" \
    : [t0] "+v"(acc0), [t1] "+v"(acc1), [t2] "+v"(acc2), [t3] "+v"(acc3) \
    : [a] "v"(A0));

#define MFMA_K7(A0, B0, B1, B2, B3) \
  asm volatile( \
    "v_mfma_f32_16x16x32_f16 %[t0], %[a], a[" #B0 "], %[t0]\n\t" \
    "v_mfma_f32_16x16x32_f16 %[t1], %[a], a[" #B1 "], %[t1]\n\t" \
    "v_mfma_f32_16x16x32_f16 %[t2], %[a], a[" #B2 "], %[t2]\n\t" \
    "v_mfma_f32_16x16x32_f16 %[t3], %[a], a[" #B3 "], %[t3]\n\t" \
    "s_nop 7\n\t" \
    "s_nop 7" \
    : [t0] "+v"(acc0), [t1] "+v"(acc1), [t2] "+v"(acc2), [t3] "+v"(acc3) \
    : [a] "v"(A0));

__global__ __launch_bounds__(256) void k2_rnn(
    const _Float16* __restrict__ Wf,
    const _Float16* __restrict__ P,
    const int* __restrict__ idx,
    const float* __restrict__ Bh,
    float* __restrict__ hout,
    float* __restrict__ hidout)
{
  const int b    = blockIdx.x;
  const int tid  = threadIdx.x;
  const int w    = tid >> 6;
  const int lane = tid & 63;
  const int quad = lane >> 4;
  __shared__ __align__(16) _Float16 hb[2][H_SZ];   // h as f16, double-buffered
  const uint4* Wf4 = (const uint4*)Wf;

  LDFRAG(0,0,  0,  1,  2,  3)  LDFRAG(0,1,  4,  5,  6,  7)
  LDFRAG(0,2,  8,  9, 10, 11)  LDFRAG(0,3, 12, 13, 14, 15)
  LDFRAG(0,4, 16, 17, 18, 19)  LDFRAG(0,5, 20, 21, 22, 23)
  LDFRAG(0,6, 24, 25, 26, 27)  LDFRAG(0,7, 28, 29, 30, 31)
  LDFRAG(1,0, 32, 33, 34, 35)  LDFRAG(1,1, 36, 37, 38, 39)
  LDFRAG(1,2, 40, 41, 42, 43)  LDFRAG(1,3, 44, 45, 46, 47)
  LDFRAG(1,4, 48, 49, 50, 51)  LDFRAG(1,5, 52, 53, 54, 55)
  LDFRAG(1,6, 56, 57, 58, 59)  LDFRAG(1,7, 60, 61, 62, 63)
  LDFRAG(2,0, 64, 65, 66, 67)  LDFRAG(2,1, 68, 69, 70, 71)
  LDFRAG(2,2, 72, 73, 74, 75)  LDFRAG(2,3, 76, 77, 78, 79)
  LDFRAG(2,4, 80, 81, 82, 83)  LDFRAG(2,5, 84, 85, 86, 87)
  LDFRAG(2,6, 88, 89, 90, 91)  LDFRAG(2,7, 92, 93, 94, 95)
  LDFRAG(3,0, 96, 97, 98, 99)  LDFRAG(3,1,100,101,102,103)
  LDFRAG(3,2,104,105,106,107)  LDFRAG(3,3,108,109,110,111)
  LDFRAG(3,4,112,113,114,115)  LDFRAG(3,5,116,117,118,119)
  LDFRAG(3,6,120,121,122,123)  LDFRAG(3,7,124,125,126,127)

  const float bhj = Bh[tid];
  const int* idxb = idx + b * T_SZ;
  int rowA = idxb[2];                               // row for t=2 (next xA refill)
  int rowB = idxb[3];                               // row for t=3 (next xB refill)
  _Float16 xA = P[(size_t)idxb[0] * H_SZ + tid];    // x for t=0
  _Float16 xB = P[(size_t)idxb[1] * H_SZ + tid];    // x for t=1
  f32x4 zero4 = {0.f, 0.f, 0.f, 0.f};
  asm volatile("" : "+v"(zero4));        // pin: no remat-mov adjacent to MFMA srcC
  hb[1][tid] = (_Float16)0.f;            // t=0 reads buffer 1 = zeros
  float hval = 0.f;
  __syncthreads();

#define K2_STEP(HR, HW, XV)                                              \
  {                                                                      \
    const _Float16* hr = (HR);                                           \
    half8 va0 = *(const half8*)(hr +   0 + quad * 8);                    \
    half8 va1 = *(const half8*)(hr +  32 + quad * 8);                    \
    half8 va2 = *(const half8*)(hr +  64 + quad * 8);                    \
    half8 va3 = *(const half8*)(hr +  96 + quad * 8);                    \
    half8 va4 = *(const half8*)(hr + 128 + quad * 8);                    \
    half8 va5 = *(const half8*)(hr + 160 + quad * 8);                    \
    half8 va6 = *(const half8*)(hr + 192 + quad * 8);                    \
    half8 va7 = *(const half8*)(hr + 224 + quad * 8);                    \
    f32x4 acc0, acc1, acc2, acc3;                                        \
    MFMA_K0(va0, zero4)                                                  \
    MFMA_KT(va1,   4:7,  36:39,  68:71, 100:103)                         \
    MFMA_KT(va2,  8:11,  40:43,  72:75, 104:107)                         \
    MFMA_KT(va3, 12:15,  44:47,  76:79, 108:111)                         \
    MFMA_KT(va4, 16:19,  48:51,  80:83, 112:115)                         \
    MFMA_KT(va5, 20:23,  52:55,  84:87, 116:119)                         \
    MFMA_KT(va6, 24:27,  56:59,  88:91, 120:123)                         \
    MFMA_K7(va7, 28:31,  60:63,  92:95, 124:127)                         \
    float v0 = acc0[0], v1 = acc1[0], v2 = acc2[0], v3 = acc3[0];        \
    float ylo = (quad & 1) ? v1 : v0;                                    \
    float yhi = (quad & 1) ? v3 : v2;                                    \
    float y   = (quad & 2) ? yhi : ylo;     /* y = (h @ Whh)[tid] */     \
    hval = fast_tanh(y + (XV) + bhj);                                    \
    (HW)[tid] = (_Float16)hval;                                          \
    __syncthreads();                                                     \
  }

#pragma unroll 1
  for (int tt = 0; tt < 256; ++tt) {
    // ---- step A: t = 2tt, read hb[1], write hb[0]
    float xvA = (float)xA;                 // wait: xA load issued 1 iter (~2 steps) ago
    xA = P[(size_t)rowA * H_SZ + tid];     // refill for t = 2tt+2 (same register)
    int t4 = 2 * tt + 4; t4 = t4 > 511 ? 511 : t4;
    rowA = idxb[t4];                       // s_load, consumed next iteration
    K2_STEP(hb[1], hb[0], xvA)
    // ---- step B: t = 2tt+1, read hb[0], write hb[1]
    float xvB = (float)xB;
    xB = P[(size_t)rowB * H_SZ + tid];     // refill for t = 2tt+3
    int t5 = 2 * tt + 5; t5 = t5 > 511 ? 511 : t5;
    rowB = idxb[t5];
    K2_STEP(hb[0], hb[1], xvB)
  }
#undef K2_STEP
  hout[b * H_SZ + tid] = hval;
  hidout[b * H_SZ + tid] = hval;
}

// ---------------- k3: out = hidden @ Wy + By  (all f32) ----------------
// Standalone 768-block shape (3 blocks/CU, 12 waves/CU): both fusion attempts
// into 64-block k2 cost +60-75 us (latency/occupancy). 4 independent accs.
__global__ __launch_bounds__(256) void k3_out(
    const float* __restrict__ h,
    const float* __restrict__ Wy,
    const float* __restrict__ By,
    float* __restrict__ out)
{
  __shared__ float hs[H_SZ];
  const int c = blockIdx.x;   // vocab chunk
  const int b = blockIdx.y;   // batch
  const int v = c * 256 + threadIdx.x;
  hs[threadIdx.x] = h[b * H_SZ + threadIdx.x];
  __syncthreads();
  float a0 = By[v], a1 = 0.f, a2 = 0.f, a3 = 0.f;
#pragma unroll 4
  for (int jj = 0; jj < H_SZ; jj += 4) {
    a0 += hs[jj + 0] * Wy[(size_t)(jj + 0) * V_SZ + v];
    a1 += hs[jj + 1] * Wy[(size_t)(jj + 1) * V_SZ + v];
    a2 += hs[jj + 2] * Wy[(size_t)(jj + 2) * V_SZ + v];
    a3 += hs[jj + 3] * Wy[(size_t)(jj + 3) * V_SZ + v];
  }
  out[(size_t)b * V_SZ + v] = (a0 + a1) + (a2 + a3);
}

extern "C" void kernel_launch(void* const* d_in, const int* in_sizes, int n_in,
                              void* d_out, int out_size, void* d_ws, size_t ws_size,
                              hipStream_t stream)
{
  const int*   idx = (const int*)d_in[0];
  const float* emb = (const float*)d_in[1];
  const float* Wxh = (const float*)d_in[2];
  const float* Whh = (const float*)d_in[3];
  const float* Wy  = (const float*)d_in[4];
  const float* By  = (const float*)d_in[5];
  const float* Bh  = (const float*)d_in[6];

  char* ws = (char*)d_ws;
  _Float16* P    = (_Float16*)(ws + WS_P);
  _Float16* Wtf  = (_Float16*)(ws + WS_WT);
  _Float16* Wf   = (_Float16*)(ws + WS_WF);
  float*    hbuf = (float*)(ws + WS_H);

  float* out    = (float*)d_out;
  float* hidout = out + (size_t)B_SZ * V_SZ;

  k0_convert<<<768, 256, 0, stream>>>(Wxh, Whh, Wtf, Wf);
  k1_xproj  <<<48, 256, 0, stream>>>(emb, Wtf, P);
  k2_rnn    <<<64, 256, 0, stream>>>(Wf, P, idx, Bh, hbuf, hidout);
  k3_out    <<<dim3(12, 64), 256, 0, stream>>>(hbuf, Wy, By, out);
}